// Round 7
// baseline (116.323 us; speedup 1.0000x reference)
//
#include <hip/hip_runtime.h>
#include <hip/hip_bf16.h>
#include <math.h>

#define NN 8192
#define EE 128
#define CAP 32   // max tracked samples per fid value (overflow -> conservative full mask)

static constexpr float INV_T = 1.0f / 0.07f;
static constexpr float LOG2E = 1.4426950408889634f;
static constexpr float LN2   = 0.6931471805599453f;
static constexpr float SENT  = -3.0e38f;

typedef __attribute__((ext_vector_type(8))) short fragAB;   // 8 bf16
typedef __attribute__((ext_vector_type(4))) float f32x4;

__device__ inline float fexp2(float x) { float r; asm("v_exp_f32 %0, %1" : "=v"(r) : "v"(x)); return r; }
__device__ inline float flog2(float x) { float r; asm("v_log_f32 %0, %1" : "=v"(r) : "v"(x)); return r; }

template<int CTRL>
__device__ inline float dpp_f(float x) {
  return __builtin_bit_cast(float,
      __builtin_amdgcn_update_dpp(0, __builtin_bit_cast(int, x), CTRL, 0xf, 0xf, true));
}
__device__ inline float red16_max(float x) {
  x = fmaxf(x, dpp_f<0xB1>(x));    // quad_perm [1,0,3,2]
  x = fmaxf(x, dpp_f<0x4E>(x));    // quad_perm [2,3,0,1]
  x = fmaxf(x, dpp_f<0x141>(x));   // row_half_mirror
  x = fmaxf(x, dpp_f<0x140>(x));   // row_mirror
  return x;
}
__device__ inline float red16_add(float x) {
  x += dpp_f<0xB1>(x); x += dpp_f<0x4E>(x); x += dpp_f<0x141>(x); x += dpp_f<0x140>(x);
  return x;
}

__device__ inline ushort f32_to_bf16_bits(float x) {
  union { float f; unsigned u; } c; c.f = x;
  unsigned u = c.u;
  u += 0x7fffu + ((u >> 16) & 1u);   // RNE
  return (ushort)(u >> 16);
}

// fp32 -> bf16 (A pre-scaled by 1/temp*log2e so scores are log2-domain),
// plus exact fp32 diagonal dot products (log2 units).
__global__ void lsl_cvt_kernel(const float* __restrict__ A, const float* __restrict__ T,
                               ushort* __restrict__ Ab, ushort* __restrict__ Tb,
                               float* __restrict__ diag) {
  const int t = blockIdx.x * 256 + threadIdx.x;
  const int i = t * 4;
  float4 a = *reinterpret_cast<const float4*>(A + i);
  float4 tt = *reinterpret_cast<const float4*>(T + i);
  ushort4 oa, ot;
  const float SC = INV_T * LOG2E;
  oa.x = f32_to_bf16_bits(a.x * SC); oa.y = f32_to_bf16_bits(a.y * SC);
  oa.z = f32_to_bf16_bits(a.z * SC); oa.w = f32_to_bf16_bits(a.w * SC);
  ot.x = f32_to_bf16_bits(tt.x); ot.y = f32_to_bf16_bits(tt.y);
  ot.z = f32_to_bf16_bits(tt.z); ot.w = f32_to_bf16_bits(tt.w);
  *reinterpret_cast<ushort4*>(Ab + i) = oa;
  *reinterpret_cast<ushort4*>(Tb + i) = ot;

  float pd = a.x * tt.x + a.y * tt.y + a.z * tt.z + a.w * tt.w;
  pd += __shfl_xor(pd, 1); pd += __shfl_xor(pd, 2); pd += __shfl_xor(pd, 4);
  pd += __shfl_xor(pd, 8); pd += __shfl_xor(pd, 16);
  if ((threadIdx.x & 31) == 0) diag[i >> 7] = pd * (INV_T * LOG2E);   // log2 units
}

// Bucket samples by fid (cnt must be pre-zeroed).
__global__ void lsl_bucket_kernel(const int* __restrict__ fids,
                                  int* __restrict__ cnt, int* __restrict__ bucket) {
  const int i = blockIdx.x * 256 + threadIdx.x;
  const int f = fids[i];
  int pos = atomicAdd(&cnt[f], 1);
  if (pos < CAP) bucket[f * CAP + pos] = i;
}

// Mark 64x64-block pairs containing an off-diagonal fid collision (flags pre-zeroed).
// Over-marking is harmless (mask path is exact); under-marking is not -> full
// fallback if a bucket overflowed (probability ~0).
__global__ void lsl_flag_kernel(const int* __restrict__ cnt, const int* __restrict__ bucket,
                                unsigned char* __restrict__ flags) {
  const int f = blockIdx.x * 256 + threadIdx.x;
  const int c = cnt[f];
  if (c < 2) return;
  if (c > CAP) {           // unknown members: conservatively mark everything
    for (int k = 0; k < 128 * 128; ++k) flags[k] = 1;
    return;
  }
  for (int a = 0; a < c; ++a) {
    const int ba = bucket[f * CAP + a] >> 6;
    for (int b = 0; b < c; ++b) {
      if (b == a) continue;
      flags[ba * 128 + (bucket[f * CAP + b] >> 6)] = 1;
    }
  }
}

// WG = 128x128 (4 waves 2x2, one 64x64 sub-tile per wave). Single-buffered
// fragment loads under a 128-reg cap -> 4 waves/SIMD. Mask pass skipped on
// sub-tiles with no fid collision (wave-uniform flag). Partial layouts
// [block][row]/[block][col] for coalesced stores; merge transposes via LDS.
__global__ __launch_bounds__(256, 4) void
lsl_tile_kernel(const ushort* __restrict__ Ab, const ushort* __restrict__ Tb,
                const int* __restrict__ fids, const unsigned char* __restrict__ flags,
                float2* __restrict__ rowp, float2* __restrict__ colp) {
  const int bid = blockIdx.x;
  const int swz = (bid & 7) * 512 + (bid >> 3);   // bijective XCD chunking (4096 WGs)
  const int tm = swz >> 6, tn = swz & 63;
  const int lane = threadIdx.x & 63;
  const int wid  = threadIdx.x >> 6;
  const int wm = wid >> 1, wn = wid & 1;
  const int rbase = tm * 128 + wm * 64;
  const int cbase = tn * 128 + wn * 64;
  const int lr = lane & 15, lg = lane >> 4;

  const ushort* abase = Ab + (size_t)(rbase + lr) * EE + lg * 8;
  const ushort* bbase = Tb + (size_t)(cbase + lr) * EE + lg * 8;

  f32x4 acc[4][4] = {};   // D: col = lane&15, row = (lane>>4)*4 + reg

#pragma unroll
  for (int ks = 0; ks < 4; ++ks) {
    fragAB av[4], bv[4];
#pragma unroll
    for (int f = 0; f < 4; ++f) {
      av[f] = *reinterpret_cast<const fragAB*>(abase + f * (16 * EE) + ks * 32);
      bv[f] = *reinterpret_cast<const fragAB*>(bbase + f * (16 * EE) + ks * 32);
    }
#pragma unroll
    for (int fm = 0; fm < 4; ++fm)
#pragma unroll
      for (int fn = 0; fn < 4; ++fn)
        acc[fm][fn] = __builtin_amdgcn_mfma_f32_16x16x32_bf16(av[fm], bv[fn], acc[fm][fn], 0, 0, 0);
  }

  // masking only where needed (wave-uniform decision)
  const bool diagtile = (rbase == cbase);
  if (diagtile || flags[(rbase >> 6) * 128 + (cbase >> 6)]) {
    int fr[4][4], fc[4];
#pragma unroll
    for (int fm = 0; fm < 4; ++fm) {
      int4 v4 = *reinterpret_cast<const int4*>(fids + rbase + fm * 16 + lg * 4);
      fr[fm][0] = v4.x; fr[fm][1] = v4.y; fr[fm][2] = v4.z; fr[fm][3] = v4.w;
    }
#pragma unroll
    for (int fn = 0; fn < 4; ++fn) fc[fn] = fids[cbase + fn * 16 + lr];

    if (diagtile) {
#pragma unroll
      for (int fm = 0; fm < 4; ++fm)
#pragma unroll
        for (int fn = 0; fn < 4; ++fn)
#pragma unroll
          for (int r = 0; r < 4; ++r) {
            bool keep = (fr[fm][r] != fc[fn]) || (fm == fn && lr == lg * 4 + r);
            acc[fm][fn][r] = keep ? acc[fm][fn][r] : SENT;
          }
    } else {
#pragma unroll
      for (int fm = 0; fm < 4; ++fm)
#pragma unroll
        for (int fn = 0; fn < 4; ++fn)
#pragma unroll
          for (int r = 0; r < 4; ++r)
            acc[fm][fn][r] = (fr[fm][r] != fc[fn]) ? acc[fm][fn][r] : SENT;
    }
  }

  // row partials over this wave's 64 cols (own-max referenced)
  const int rblk = tn * 2 + wn;
#pragma unroll
  for (int fm = 0; fm < 4; ++fm)
#pragma unroll
    for (int r = 0; r < 4; ++r) {
      float m = fmaxf(fmaxf(acc[fm][0][r], acc[fm][1][r]), fmaxf(acc[fm][2][r], acc[fm][3][r]));
      m = red16_max(m);
      float s = fexp2(acc[fm][0][r] - m) + fexp2(acc[fm][1][r] - m)
              + fexp2(acc[fm][2][r] - m) + fexp2(acc[fm][3][r] - m);
      s = red16_add(s);
      if (lr == 0)
        rowp[(size_t)rblk * NN + (rbase + fm * 16 + lg * 4 + r)] = make_float2(m, s);
    }

  // col partials over this wave's 64 rows (own-max referenced)
  const int cblk = tm * 2 + wm;
#pragma unroll
  for (int fn = 0; fn < 4; ++fn) {
    float cm = SENT;
#pragma unroll
    for (int fm = 0; fm < 4; ++fm)
#pragma unroll
      for (int r = 0; r < 4; ++r) cm = fmaxf(cm, acc[fm][fn][r]);
    cm = fmaxf(cm, __shfl_xor(cm, 16));
    cm = fmaxf(cm, __shfl_xor(cm, 32));
    float c = 0.f;
#pragma unroll
    for (int fm = 0; fm < 4; ++fm)
#pragma unroll
      for (int r = 0; r < 4; ++r) c += fexp2(acc[fm][fn][r] - cm);
    c += __shfl_xor(c, 16);
    c += __shfl_xor(c, 32);
    if (lg == 0)
      colp[(size_t)cblk * NN + (cbase + fn * 16 + lr)] = make_float2(cm, c);
  }
}

// WG handles 32 samples: stage [128 blocks][32 samples] slab through padded LDS
// (coalesced global reads), 8 threads per sample merge 128 partials in 2 passes.
__global__ __launch_bounds__(256) void
lsl_merge_kernel(const float2* __restrict__ rowp, const float2* __restrict__ colp,
                 const float* __restrict__ diag, float* __restrict__ bsum) {
  __shared__ float2 sl[128 * 33];
  __shared__ float2 red[32][8];
  const int tid = threadIdx.x;
  const int ibase = blockIdx.x * 32;
  const int s = tid & 31, p = tid >> 5;

  float lse0 = 0.f, lse1 = 0.f;
#pragma unroll
  for (int pass = 0; pass < 2; ++pass) {
    const float2* __restrict__ src = pass ? colp : rowp;
#pragma unroll
    for (int k = 0; k < 16; ++k) {
      int L = tid + k * 256;
      int b = L >> 5, di = L & 31;
      sl[b * 33 + di] = src[(size_t)b * NN + ibase + di];
    }
    __syncthreads();
    float m = SENT;
#pragma unroll
    for (int k = 0; k < 16; ++k) m = fmaxf(m, sl[(p * 16 + k) * 33 + s].x);
    float sum = 0.f;
#pragma unroll
    for (int k = 0; k < 16; ++k) {
      float2 v = sl[(p * 16 + k) * 33 + s];
      sum += v.y * fexp2(v.x - m);
    }
    red[s][p] = make_float2(m, sum);
    __syncthreads();
    if (p == 0) {
      float M = SENT;
#pragma unroll
      for (int k = 0; k < 8; ++k) M = fmaxf(M, red[s][k].x);
      float S = 0.f;
#pragma unroll
      for (int k = 0; k < 8; ++k) S += red[s][k].y * fexp2(red[s][k].x - M);
      if (pass == 0) lse0 = M + flog2(S); else lse1 = M + flog2(S);
    }
    __syncthreads();
  }

  if (tid < 32) {
    float loss = lse0 + lse1 - 2.f * diag[ibase + tid];   // log2 units
#pragma unroll
    for (int d = 1; d < 32; d <<= 1) loss += __shfl_xor(loss, d);
    if (tid == 0) bsum[blockIdx.x] = loss;
  }
}

__global__ __launch_bounds__(256) void
lsl_final_kernel(const float* __restrict__ bsum, float* __restrict__ out) {
  float v = bsum[threadIdx.x];
#pragma unroll
  for (int d = 1; d < 64; d <<= 1) v += __shfl_xor(v, d);
  __shared__ float l4[4];
  if ((threadIdx.x & 63) == 0) l4[threadIdx.x >> 6] = v;
  __syncthreads();
  if (threadIdx.x == 0) out[0] = (l4[0] + l4[1] + l4[2] + l4[3]) * (LN2 / (float)NN);
}

extern "C" void kernel_launch(void* const* d_in, const int* in_sizes, int n_in,
                              void* d_out, int out_size, void* d_ws, size_t ws_size,
                              hipStream_t stream) {
  const float* A = (const float*)d_in[0];
  const float* T = (const float*)d_in[1];
  const int* fids = (const int*)d_in[2];
  float* out = (float*)d_out;
  char* ws = (char*)d_ws;

  // ws: Ab 2MB | Tb 2MB | diag 32KB | rowp 8MB | colp 8MB | bsum 1KB | cnt 16KB | bucket 512KB | flags 16KB
  size_t off = 0;
  ushort* Ab  = (ushort*)(ws + off); off += (size_t)NN * EE * 2;
  ushort* Tb  = (ushort*)(ws + off); off += (size_t)NN * EE * 2;
  float* diag = (float*)(ws + off);  off += (size_t)NN * 4;
  float2* rowp = (float2*)(ws + off); off += (size_t)NN * 128 * 8;
  float2* colp = (float2*)(ws + off); off += (size_t)NN * 128 * 8;
  float* bsum = (float*)(ws + off);  off += 1024;
  int* cnt    = (int*)(ws + off);    off += 4096 * 4;
  int* bucket = (int*)(ws + off);    off += (size_t)4096 * CAP * 4;
  unsigned char* flags = (unsigned char*)(ws + off); off += 128 * 128;

  hipMemsetAsync(cnt, 0, 4096 * 4, stream);
  hipMemsetAsync(flags, 0, 128 * 128, stream);
  hipLaunchKernelGGL(lsl_cvt_kernel, dim3(NN * EE / 4 / 256), dim3(256), 0, stream, A, T, Ab, Tb, diag);
  hipLaunchKernelGGL(lsl_bucket_kernel, dim3(NN / 256), dim3(256), 0, stream, fids, cnt, bucket);
  hipLaunchKernelGGL(lsl_flag_kernel, dim3(4096 / 256), dim3(256), 0, stream, cnt, bucket, flags);
  hipLaunchKernelGGL(lsl_tile_kernel, dim3(4096), dim3(256), 0, stream, Ab, Tb, fids, flags, rowp, colp);
  hipLaunchKernelGGL(lsl_merge_kernel, dim3(NN / 32), dim3(256), 0, stream, rowp, colp, diag, bsum);
  hipLaunchKernelGGL(lsl_final_kernel, dim3(1), dim3(256), 0, stream, bsum, out);
}

// Round 8
// 87.122 us; speedup vs baseline: 1.3352x; 1.3352x over previous
//
#include <hip/hip_runtime.h>
#include <hip/hip_bf16.h>
#include <math.h>

#define NN 8192
#define EE 128

static constexpr float INV_T = 1.0f / 0.07f;
static constexpr float LOG2E = 1.4426950408889634f;
static constexpr float LN2   = 0.6931471805599453f;
static constexpr float SENT  = -3.0e38f;

typedef __attribute__((ext_vector_type(8))) short fragAB;   // 8 bf16
typedef __attribute__((ext_vector_type(4))) float f32x4;

__device__ inline float fexp2(float x) { float r; asm("v_exp_f32 %0, %1" : "=v"(r) : "v"(x)); return r; }
__device__ inline float flog2(float x) { float r; asm("v_log_f32 %0, %1" : "=v"(r) : "v"(x)); return r; }

template<int CTRL>
__device__ inline float dpp_f(float x) {
  return __builtin_bit_cast(float,
      __builtin_amdgcn_update_dpp(0, __builtin_bit_cast(int, x), CTRL, 0xf, 0xf, true));
}
__device__ inline float red16_max(float x) {
  x = fmaxf(x, dpp_f<0xB1>(x));    // quad_perm [1,0,3,2]
  x = fmaxf(x, dpp_f<0x4E>(x));    // quad_perm [2,3,0,1]
  x = fmaxf(x, dpp_f<0x141>(x));   // row_half_mirror
  x = fmaxf(x, dpp_f<0x140>(x));   // row_mirror
  return x;
}
__device__ inline float red16_add(float x) {
  x += dpp_f<0xB1>(x); x += dpp_f<0x4E>(x); x += dpp_f<0x141>(x); x += dpp_f<0x140>(x);
  return x;
}

__device__ inline ushort f32_to_bf16_bits(float x) {
  union { float f; unsigned u; } c; c.f = x;
  unsigned u = c.u;
  u += 0x7fffu + ((u >> 16) & 1u);   // RNE
  return (ushort)(u >> 16);
}

// fp32 -> bf16 (A pre-scaled by 1/temp*log2e so scores are log2-domain),
// plus exact fp32 diagonal dot products (log2 units).
__global__ void lsl_cvt_kernel(const float* __restrict__ A, const float* __restrict__ T,
                               ushort* __restrict__ Ab, ushort* __restrict__ Tb,
                               float* __restrict__ diag) {
  const int t = blockIdx.x * 256 + threadIdx.x;
  const int i = t * 4;
  float4 a = *reinterpret_cast<const float4*>(A + i);
  float4 tt = *reinterpret_cast<const float4*>(T + i);
  ushort4 oa, ot;
  const float SC = INV_T * LOG2E;
  oa.x = f32_to_bf16_bits(a.x * SC); oa.y = f32_to_bf16_bits(a.y * SC);
  oa.z = f32_to_bf16_bits(a.z * SC); oa.w = f32_to_bf16_bits(a.w * SC);
  ot.x = f32_to_bf16_bits(tt.x); ot.y = f32_to_bf16_bits(tt.y);
  ot.z = f32_to_bf16_bits(tt.z); ot.w = f32_to_bf16_bits(tt.w);
  *reinterpret_cast<ushort4*>(Ab + i) = oa;
  *reinterpret_cast<ushort4*>(Tb + i) = ot;

  float pd = a.x * tt.x + a.y * tt.y + a.z * tt.z + a.w * tt.w;
  pd += __shfl_xor(pd, 1); pd += __shfl_xor(pd, 2); pd += __shfl_xor(pd, 4);
  pd += __shfl_xor(pd, 8); pd += __shfl_xor(pd, 16);
  if ((threadIdx.x & 31) == 0) diag[i >> 7] = pd * (INV_T * LOG2E);   // log2 units
}

#define LDFRAG(av, bv, ks)                                                        \
  _Pragma("unroll") for (int f = 0; f < 4; ++f) {                                 \
    av[f] = *reinterpret_cast<const fragAB*>(abase + f * (16 * EE) + (ks) * 32);  \
    bv[f] = *reinterpret_cast<const fragAB*>(bbase + f * (16 * EE) + (ks) * 32);  \
  }
#define MMAC(av, bv)                                                              \
  _Pragma("unroll") for (int fm = 0; fm < 4; ++fm)                                \
    _Pragma("unroll") for (int fn = 0; fn < 4; ++fn)                              \
      acc[fm][fn] = __builtin_amdgcn_mfma_f32_16x16x32_bf16(av[fm], bv[fn], acc[fm][fn], 0, 0, 0);

// WG = 128x128 (4 waves 2x2, one 64x64 sub-tile per wave). Double-buffered
// fragment loads. Stage-major epilogue: independent reduction chains batched
// per stage so DPP / LDS-pipe latencies overlap. Partial layouts [block][row]
// for coalesced stores; merge kernel transposes through LDS.
__global__ __launch_bounds__(256, 3) void
lsl_tile_kernel(const ushort* __restrict__ Ab, const ushort* __restrict__ Tb,
                const int* __restrict__ fids,
                float2* __restrict__ rowp, float2* __restrict__ colp) {
  const int bid = blockIdx.x;
  const int swz = (bid & 7) * 512 + (bid >> 3);   // bijective XCD chunking (4096 WGs)
  const int tm = swz >> 6, tn = swz & 63;
  const int lane = threadIdx.x & 63;
  const int wid  = threadIdx.x >> 6;
  const int wm = wid >> 1, wn = wid & 1;
  const int rbase = tm * 128 + wm * 64;
  const int cbase = tn * 128 + wn * 64;
  const int lr = lane & 15, lg = lane >> 4;

  const ushort* abase = Ab + (size_t)(rbase + lr) * EE + lg * 8;
  const ushort* bbase = Tb + (size_t)(cbase + lr) * EE + lg * 8;

  f32x4 acc[4][4] = {};   // D: col = lane&15, row = (lane>>4)*4 + reg
  fragAB a0[4], b0[4], a1[4], b1[4];

  LDFRAG(a0, b0, 0)
  LDFRAG(a1, b1, 1)
  MMAC(a0, b0)
  LDFRAG(a0, b0, 2)
  MMAC(a1, b1)
  LDFRAG(a1, b1, 3)
  MMAC(a0, b0)
  MMAC(a1, b1)

  // fids + branchless mask -> sentinel (diagonal kept; only when rbase == cbase)
  int fr[4][4], fc[4];
#pragma unroll
  for (int fm = 0; fm < 4; ++fm) {
    int4 v4 = *reinterpret_cast<const int4*>(fids + rbase + fm * 16 + lg * 4);
    fr[fm][0] = v4.x; fr[fm][1] = v4.y; fr[fm][2] = v4.z; fr[fm][3] = v4.w;
  }
#pragma unroll
  for (int fn = 0; fn < 4; ++fn) fc[fn] = fids[cbase + fn * 16 + lr];

  if (rbase == cbase) {
#pragma unroll
    for (int fm = 0; fm < 4; ++fm)
#pragma unroll
      for (int fn = 0; fn < 4; ++fn)
#pragma unroll
        for (int r = 0; r < 4; ++r) {
          bool keep = (fr[fm][r] != fc[fn]) || (fm == fn && lr == lg * 4 + r);
          acc[fm][fn][r] = keep ? acc[fm][fn][r] : SENT;
        }
  } else {
#pragma unroll
    for (int fm = 0; fm < 4; ++fm)
#pragma unroll
      for (int fn = 0; fn < 4; ++fn)
#pragma unroll
        for (int r = 0; r < 4; ++r)
          acc[fm][fn][r] = (fr[fm][r] != fc[fn]) ? acc[fm][fn][r] : SENT;
  }

  // ---------- row pass, stage-major ----------
  // Stage R1: all 16 in-lane max trees + red16 chains (independent, batched)
  float rm[4][4];
#pragma unroll
  for (int fm = 0; fm < 4; ++fm)
#pragma unroll
    for (int r = 0; r < 4; ++r)
      rm[fm][r] = fmaxf(fmaxf(acc[fm][0][r], acc[fm][1][r]),
                        fmaxf(acc[fm][2][r], acc[fm][3][r]));
#pragma unroll
  for (int fm = 0; fm < 4; ++fm)
#pragma unroll
    for (int r = 0; r < 4; ++r)
      rm[fm][r] = red16_max(rm[fm][r]);

  // Stage R2: all exps + sum trees + red16_add chains (batched)
  float rs[4][4];
#pragma unroll
  for (int fm = 0; fm < 4; ++fm)
#pragma unroll
    for (int r = 0; r < 4; ++r)
      rs[fm][r] = (fexp2(acc[fm][0][r] - rm[fm][r]) + fexp2(acc[fm][1][r] - rm[fm][r]))
                + (fexp2(acc[fm][2][r] - rm[fm][r]) + fexp2(acc[fm][3][r] - rm[fm][r]));
#pragma unroll
  for (int fm = 0; fm < 4; ++fm)
#pragma unroll
    for (int r = 0; r < 4; ++r)
      rs[fm][r] = red16_add(rs[fm][r]);

  const int rblk = tn * 2 + wn;
  if (lr == 0) {
#pragma unroll
    for (int fm = 0; fm < 4; ++fm)
#pragma unroll
      for (int r = 0; r < 4; ++r)
        rowp[(size_t)rblk * NN + (rbase + fm * 16 + lg * 4 + r)] = make_float2(rm[fm][r], rs[fm][r]);
  }

  // ---------- col pass, stage-major ----------
  // Stage C1: 4 independent in-lane max trees (depth 4)
  float cm[4];
#pragma unroll
  for (int fn = 0; fn < 4; ++fn) {
    float m0 = fmaxf(fmaxf(acc[0][fn][0], acc[0][fn][1]), fmaxf(acc[0][fn][2], acc[0][fn][3]));
    float m1 = fmaxf(fmaxf(acc[1][fn][0], acc[1][fn][1]), fmaxf(acc[1][fn][2], acc[1][fn][3]));
    float m2 = fmaxf(fmaxf(acc[2][fn][0], acc[2][fn][1]), fmaxf(acc[2][fn][2], acc[2][fn][3]));
    float m3 = fmaxf(fmaxf(acc[3][fn][0], acc[3][fn][1]), fmaxf(acc[3][fn][2], acc[3][fn][3]));
    cm[fn] = fmaxf(fmaxf(m0, m1), fmaxf(m2, m3));
  }
  // Stage C2: batched cross-lane maxes (4 shfls in flight per step)
  {
    float t0 = __shfl_xor(cm[0], 16), t1 = __shfl_xor(cm[1], 16),
          t2 = __shfl_xor(cm[2], 16), t3 = __shfl_xor(cm[3], 16);
    cm[0] = fmaxf(cm[0], t0); cm[1] = fmaxf(cm[1], t1);
    cm[2] = fmaxf(cm[2], t2); cm[3] = fmaxf(cm[3], t3);
    t0 = __shfl_xor(cm[0], 32); t1 = __shfl_xor(cm[1], 32);
    t2 = __shfl_xor(cm[2], 32); t3 = __shfl_xor(cm[3], 32);
    cm[0] = fmaxf(cm[0], t0); cm[1] = fmaxf(cm[1], t1);
    cm[2] = fmaxf(cm[2], t2); cm[3] = fmaxf(cm[3], t3);
  }
  // Stage C3: 64 independent exps, pairwise sum trees (depth 4)
  float cs[4];
#pragma unroll
  for (int fn = 0; fn < 4; ++fn) {
    float s0 = (fexp2(acc[0][fn][0] - cm[fn]) + fexp2(acc[0][fn][1] - cm[fn]))
             + (fexp2(acc[0][fn][2] - cm[fn]) + fexp2(acc[0][fn][3] - cm[fn]));
    float s1 = (fexp2(acc[1][fn][0] - cm[fn]) + fexp2(acc[1][fn][1] - cm[fn]))
             + (fexp2(acc[1][fn][2] - cm[fn]) + fexp2(acc[1][fn][3] - cm[fn]));
    float s2 = (fexp2(acc[2][fn][0] - cm[fn]) + fexp2(acc[2][fn][1] - cm[fn]))
             + (fexp2(acc[2][fn][2] - cm[fn]) + fexp2(acc[2][fn][3] - cm[fn]));
    float s3 = (fexp2(acc[3][fn][0] - cm[fn]) + fexp2(acc[3][fn][1] - cm[fn]))
             + (fexp2(acc[3][fn][2] - cm[fn]) + fexp2(acc[3][fn][3] - cm[fn]));
    cs[fn] = (s0 + s1) + (s2 + s3);
  }
  // Stage C4: batched cross-lane sums
  {
    float t0 = __shfl_xor(cs[0], 16), t1 = __shfl_xor(cs[1], 16),
          t2 = __shfl_xor(cs[2], 16), t3 = __shfl_xor(cs[3], 16);
    cs[0] += t0; cs[1] += t1; cs[2] += t2; cs[3] += t3;
    t0 = __shfl_xor(cs[0], 32); t1 = __shfl_xor(cs[1], 32);
    t2 = __shfl_xor(cs[2], 32); t3 = __shfl_xor(cs[3], 32);
    cs[0] += t0; cs[1] += t1; cs[2] += t2; cs[3] += t3;
  }

  const int cblk = tm * 2 + wm;
  if (lg == 0) {
#pragma unroll
    for (int fn = 0; fn < 4; ++fn)
      colp[(size_t)cblk * NN + (cbase + fn * 16 + lr)] = make_float2(cm[fn], cs[fn]);
  }
}

// WG handles 32 samples: stage [128 blocks][32 samples] slab through padded LDS
// (coalesced global reads), 8 threads per sample merge 128 partials in 2 passes.
__global__ __launch_bounds__(256) void
lsl_merge_kernel(const float2* __restrict__ rowp, const float2* __restrict__ colp,
                 const float* __restrict__ diag, float* __restrict__ bsum) {
  __shared__ float2 sl[128 * 33];
  __shared__ float2 red[32][8];
  const int tid = threadIdx.x;
  const int ibase = blockIdx.x * 32;
  const int s = tid & 31, p = tid >> 5;

  float lse0 = 0.f, lse1 = 0.f;
#pragma unroll
  for (int pass = 0; pass < 2; ++pass) {
    const float2* __restrict__ src = pass ? colp : rowp;
#pragma unroll
    for (int k = 0; k < 16; ++k) {
      int L = tid + k * 256;
      int b = L >> 5, di = L & 31;
      sl[b * 33 + di] = src[(size_t)b * NN + ibase + di];
    }
    __syncthreads();
    float m = SENT;
#pragma unroll
    for (int k = 0; k < 16; ++k) m = fmaxf(m, sl[(p * 16 + k) * 33 + s].x);
    float sum = 0.f;
#pragma unroll
    for (int k = 0; k < 16; ++k) {
      float2 v = sl[(p * 16 + k) * 33 + s];
      sum += v.y * fexp2(v.x - m);
    }
    red[s][p] = make_float2(m, sum);
    __syncthreads();
    if (p == 0) {
      float M = SENT;
#pragma unroll
      for (int k = 0; k < 8; ++k) M = fmaxf(M, red[s][k].x);
      float S = 0.f;
#pragma unroll
      for (int k = 0; k < 8; ++k) S += red[s][k].y * fexp2(red[s][k].x - M);
      if (pass == 0) lse0 = M + flog2(S); else lse1 = M + flog2(S);
    }
    __syncthreads();
  }

  if (tid < 32) {
    float loss = lse0 + lse1 - 2.f * diag[ibase + tid];   // log2 units
#pragma unroll
    for (int d = 1; d < 32; d <<= 1) loss += __shfl_xor(loss, d);
    if (tid == 0) bsum[blockIdx.x] = loss;
  }
}

__global__ __launch_bounds__(256) void
lsl_final_kernel(const float* __restrict__ bsum, float* __restrict__ out) {
  float v = bsum[threadIdx.x];
#pragma unroll
  for (int d = 1; d < 64; d <<= 1) v += __shfl_xor(v, d);
  __shared__ float l4[4];
  if ((threadIdx.x & 63) == 0) l4[threadIdx.x >> 6] = v;
  __syncthreads();
  if (threadIdx.x == 0) out[0] = (l4[0] + l4[1] + l4[2] + l4[3]) * (LN2 / (float)NN);
}

extern "C" void kernel_launch(void* const* d_in, const int* in_sizes, int n_in,
                              void* d_out, int out_size, void* d_ws, size_t ws_size,
                              hipStream_t stream) {
  const float* A = (const float*)d_in[0];
  const float* T = (const float*)d_in[1];
  const int* fids = (const int*)d_in[2];
  float* out = (float*)d_out;
  char* ws = (char*)d_ws;

  // ws: Ab 2MB | Tb 2MB | diag 32KB | rowp 8MB | colp 8MB | bsum 1KB
  size_t off = 0;
  ushort* Ab  = (ushort*)(ws + off); off += (size_t)NN * EE * 2;
  ushort* Tb  = (ushort*)(ws + off); off += (size_t)NN * EE * 2;
  float* diag = (float*)(ws + off);  off += (size_t)NN * 4;
  float2* rowp = (float2*)(ws + off); off += (size_t)NN * 128 * 8;
  float2* colp = (float2*)(ws + off); off += (size_t)NN * 128 * 8;
  float* bsum = (float*)(ws + off);  off += 1024;

  hipLaunchKernelGGL(lsl_cvt_kernel, dim3(NN * EE / 4 / 256), dim3(256), 0, stream, A, T, Ab, Tb, diag);
  hipLaunchKernelGGL(lsl_tile_kernel, dim3(4096), dim3(256), 0, stream, Ab, Tb, fids, rowp, colp);
  hipLaunchKernelGGL(lsl_merge_kernel, dim3(NN / 32), dim3(256), 0, stream, rowp, colp, diag, bsum);
  hipLaunchKernelGGL(lsl_final_kernel, dim3(1), dim3(256), 0, stream, bsum, out);
}

// Round 9
// 64.325 us; speedup vs baseline: 1.8084x; 1.3544x over previous
//
#include <hip/hip_runtime.h>
#include <hip/hip_bf16.h>
#include <math.h>

#define NN 8192
#define EE 128

static constexpr float INV_T = 1.0f / 0.07f;
static constexpr float LOG2E = 1.4426950408889634f;
static constexpr float LN2   = 0.6931471805599453f;
static constexpr float SENT  = -3.0e38f;

typedef __attribute__((ext_vector_type(8))) short fragAB;   // 8 bf16
typedef __attribute__((ext_vector_type(4))) float f32x4;
typedef const __attribute__((address_space(1))) void gvoid;
typedef __attribute__((address_space(3))) void lvoid;

__device__ inline float fexp2(float x) { float r; asm("v_exp_f32 %0, %1" : "=v"(r) : "v"(x)); return r; }
__device__ inline float flog2(float x) { float r; asm("v_log_f32 %0, %1" : "=v"(r) : "v"(x)); return r; }

template<int CTRL>
__device__ inline float dpp_f(float x) {
  return __builtin_bit_cast(float,
      __builtin_amdgcn_update_dpp(0, __builtin_bit_cast(int, x), CTRL, 0xf, 0xf, true));
}
__device__ inline float red16_max(float x) {
  x = fmaxf(x, dpp_f<0xB1>(x));    // quad_perm [1,0,3,2]
  x = fmaxf(x, dpp_f<0x4E>(x));    // quad_perm [2,3,0,1]
  x = fmaxf(x, dpp_f<0x141>(x));   // row_half_mirror
  x = fmaxf(x, dpp_f<0x140>(x));   // row_mirror
  return x;
}
__device__ inline float red16_add(float x) {
  x += dpp_f<0xB1>(x); x += dpp_f<0x4E>(x); x += dpp_f<0x141>(x); x += dpp_f<0x140>(x);
  return x;
}

__device__ inline ushort f32_to_bf16_bits(float x) {
  union { float f; unsigned u; } c; c.f = x;
  unsigned u = c.u;
  u += 0x7fffu + ((u >> 16) & 1u);   // RNE
  return (ushort)(u >> 16);
}

// fp32 -> bf16 (A pre-scaled by 1/temp*log2e so scores are log2-domain),
// plus exact fp32 diagonal dot products (log2 units).
__global__ void lsl_cvt_kernel(const float* __restrict__ A, const float* __restrict__ T,
                               ushort* __restrict__ Ab, ushort* __restrict__ Tb,
                               float* __restrict__ diag) {
  const int t = blockIdx.x * 256 + threadIdx.x;
  const int i = t * 4;
  float4 a = *reinterpret_cast<const float4*>(A + i);
  float4 tt = *reinterpret_cast<const float4*>(T + i);
  ushort4 oa, ot;
  const float SC = INV_T * LOG2E;
  oa.x = f32_to_bf16_bits(a.x * SC); oa.y = f32_to_bf16_bits(a.y * SC);
  oa.z = f32_to_bf16_bits(a.z * SC); oa.w = f32_to_bf16_bits(a.w * SC);
  ot.x = f32_to_bf16_bits(tt.x); ot.y = f32_to_bf16_bits(tt.y);
  ot.z = f32_to_bf16_bits(tt.z); ot.w = f32_to_bf16_bits(tt.w);
  *reinterpret_cast<ushort4*>(Ab + i) = oa;
  *reinterpret_cast<ushort4*>(Tb + i) = ot;

  float pd = a.x * tt.x + a.y * tt.y + a.z * tt.z + a.w * tt.w;
  pd += __shfl_xor(pd, 1); pd += __shfl_xor(pd, 2); pd += __shfl_xor(pd, 4);
  pd += __shfl_xor(pd, 8); pd += __shfl_xor(pd, 16);
  if ((threadIdx.x & 31) == 0) diag[i >> 7] = pd * (INV_T * LOG2E);   // log2 units
}

#define MMAC(av, bv)                                                              \
  _Pragma("unroll") for (int fm = 0; fm < 4; ++fm)                                \
    _Pragma("unroll") for (int fn = 0; fn < 4; ++fn)                              \
      acc[fm][fn] = __builtin_amdgcn_mfma_f32_16x16x32_bf16(av[fm], bv[fn], acc[fm][fn], 0, 0, 0);

// WG = 128x128 tile (4 waves 2x2, 64x64 per wave). Full A/B tiles staged to
// LDS via global_load_lds width-16 (one async burst, one barrier). LDS is
// XOR-swizzled (col16 ^= row&15) with linear dest + pre-swizzled global
// source (rule: both-sides-or-neither); ds_read_b128 applies the same XOR.
// Stage-major epilogue; partial layouts [block][row] for coalesced stores.
__global__ __launch_bounds__(256, 2) void
lsl_tile_kernel(const ushort* __restrict__ Ab, const ushort* __restrict__ Tb,
                const int* __restrict__ fids,
                float2* __restrict__ rowp, float2* __restrict__ colp) {
  __shared__ ushort As[128 * 128];
  __shared__ ushort Bs[128 * 128];

  const int bid = blockIdx.x;
  const int swz = (bid & 7) * 512 + (bid >> 3);   // bijective XCD chunking (4096 WGs)
  const int tm = swz >> 6, tn = swz & 63;
  const int tid = threadIdx.x;
  const int lane = tid & 63;
  const int wid  = tid >> 6;
  const int wm = wid >> 1, wn = wid & 1;
  const int rbase = tm * 128 + wm * 64;
  const int cbase = tn * 128 + wn * 64;
  const int lr = lane & 15, lg = lane >> 4;

  // ---- stage both tiles: linear LDS dest, pre-swizzled global source ----
  // storage slot (row, c') holds global 16B-chunk c = c' ^ (row&15)
  {
    const int trow = tid >> 4;              // 0..15 within 16-row stripe
    const int scol = ((tid & 15) ^ trow) * 8;
    const ushort* gA = Ab + (size_t)(tm * 128 + trow) * EE + scol;
    const ushort* gB = Tb + (size_t)(tn * 128 + trow) * EE + scol;
#pragma unroll
    for (int i = 0; i < 8; ++i)
      __builtin_amdgcn_global_load_lds((gvoid*)(gA + (size_t)i * 16 * EE),
          (lvoid*)((char*)As + i * 4096 + wid * 1024), 16, 0, 0);
#pragma unroll
    for (int i = 0; i < 8; ++i)
      __builtin_amdgcn_global_load_lds((gvoid*)(gB + (size_t)i * 16 * EE),
          (lvoid*)((char*)Bs + i * 4096 + wid * 1024), 16, 0, 0);
  }
  __syncthreads();

  // ---- compute from LDS ----
  f32x4 acc[4][4] = {};   // D: col = lane&15, row = (lane>>4)*4 + reg
#pragma unroll
  for (int ks = 0; ks < 4; ++ks) {
    fragAB av[4], bv[4];
#pragma unroll
    for (int f = 0; f < 4; ++f) {
      av[f] = *reinterpret_cast<const fragAB*>(
          &As[(wm * 64 + f * 16 + lr) * 128 + (((ks * 4 + lg) ^ lr) * 8)]);
      bv[f] = *reinterpret_cast<const fragAB*>(
          &Bs[(wn * 64 + f * 16 + lr) * 128 + (((ks * 4 + lg) ^ lr) * 8)]);
    }
    MMAC(av, bv)
  }

  // fids + branchless mask -> sentinel (diagonal kept; only when rbase == cbase)
  int fr[4][4], fc[4];
#pragma unroll
  for (int fm = 0; fm < 4; ++fm) {
    int4 v4 = *reinterpret_cast<const int4*>(fids + rbase + fm * 16 + lg * 4);
    fr[fm][0] = v4.x; fr[fm][1] = v4.y; fr[fm][2] = v4.z; fr[fm][3] = v4.w;
  }
#pragma unroll
  for (int fn = 0; fn < 4; ++fn) fc[fn] = fids[cbase + fn * 16 + lr];

  if (rbase == cbase) {
#pragma unroll
    for (int fm = 0; fm < 4; ++fm)
#pragma unroll
      for (int fn = 0; fn < 4; ++fn)
#pragma unroll
        for (int r = 0; r < 4; ++r) {
          bool keep = (fr[fm][r] != fc[fn]) || (fm == fn && lr == lg * 4 + r);
          acc[fm][fn][r] = keep ? acc[fm][fn][r] : SENT;
        }
  } else {
#pragma unroll
    for (int fm = 0; fm < 4; ++fm)
#pragma unroll
      for (int fn = 0; fn < 4; ++fn)
#pragma unroll
        for (int r = 0; r < 4; ++r)
          acc[fm][fn][r] = (fr[fm][r] != fc[fn]) ? acc[fm][fn][r] : SENT;
  }

  // ---------- row pass, stage-major ----------
  float rm[4][4];
#pragma unroll
  for (int fm = 0; fm < 4; ++fm)
#pragma unroll
    for (int r = 0; r < 4; ++r)
      rm[fm][r] = fmaxf(fmaxf(acc[fm][0][r], acc[fm][1][r]),
                        fmaxf(acc[fm][2][r], acc[fm][3][r]));
#pragma unroll
  for (int fm = 0; fm < 4; ++fm)
#pragma unroll
    for (int r = 0; r < 4; ++r)
      rm[fm][r] = red16_max(rm[fm][r]);

  float rs[4][4];
#pragma unroll
  for (int fm = 0; fm < 4; ++fm)
#pragma unroll
    for (int r = 0; r < 4; ++r)
      rs[fm][r] = (fexp2(acc[fm][0][r] - rm[fm][r]) + fexp2(acc[fm][1][r] - rm[fm][r]))
                + (fexp2(acc[fm][2][r] - rm[fm][r]) + fexp2(acc[fm][3][r] - rm[fm][r]));
#pragma unroll
  for (int fm = 0; fm < 4; ++fm)
#pragma unroll
    for (int r = 0; r < 4; ++r)
      rs[fm][r] = red16_add(rs[fm][r]);

  const int rblk = tn * 2 + wn;
  if (lr == 0) {
#pragma unroll
    for (int fm = 0; fm < 4; ++fm)
#pragma unroll
      for (int r = 0; r < 4; ++r)
        rowp[(size_t)rblk * NN + (rbase + fm * 16 + lg * 4 + r)] = make_float2(rm[fm][r], rs[fm][r]);
  }

  // ---------- col pass, stage-major ----------
  float cm[4];
#pragma unroll
  for (int fn = 0; fn < 4; ++fn) {
    float m0 = fmaxf(fmaxf(acc[0][fn][0], acc[0][fn][1]), fmaxf(acc[0][fn][2], acc[0][fn][3]));
    float m1 = fmaxf(fmaxf(acc[1][fn][0], acc[1][fn][1]), fmaxf(acc[1][fn][2], acc[1][fn][3]));
    float m2 = fmaxf(fmaxf(acc[2][fn][0], acc[2][fn][1]), fmaxf(acc[2][fn][2], acc[2][fn][3]));
    float m3 = fmaxf(fmaxf(acc[3][fn][0], acc[3][fn][1]), fmaxf(acc[3][fn][2], acc[3][fn][3]));
    cm[fn] = fmaxf(fmaxf(m0, m1), fmaxf(m2, m3));
  }
  {
    float t0 = __shfl_xor(cm[0], 16), t1 = __shfl_xor(cm[1], 16),
          t2 = __shfl_xor(cm[2], 16), t3 = __shfl_xor(cm[3], 16);
    cm[0] = fmaxf(cm[0], t0); cm[1] = fmaxf(cm[1], t1);
    cm[2] = fmaxf(cm[2], t2); cm[3] = fmaxf(cm[3], t3);
    t0 = __shfl_xor(cm[0], 32); t1 = __shfl_xor(cm[1], 32);
    t2 = __shfl_xor(cm[2], 32); t3 = __shfl_xor(cm[3], 32);
    cm[0] = fmaxf(cm[0], t0); cm[1] = fmaxf(cm[1], t1);
    cm[2] = fmaxf(cm[2], t2); cm[3] = fmaxf(cm[3], t3);
  }
  float cs[4];
#pragma unroll
  for (int fn = 0; fn < 4; ++fn) {
    float s0 = (fexp2(acc[0][fn][0] - cm[fn]) + fexp2(acc[0][fn][1] - cm[fn]))
             + (fexp2(acc[0][fn][2] - cm[fn]) + fexp2(acc[0][fn][3] - cm[fn]));
    float s1 = (fexp2(acc[1][fn][0] - cm[fn]) + fexp2(acc[1][fn][1] - cm[fn]))
             + (fexp2(acc[1][fn][2] - cm[fn]) + fexp2(acc[1][fn][3] - cm[fn]));
    float s2 = (fexp2(acc[2][fn][0] - cm[fn]) + fexp2(acc[2][fn][1] - cm[fn]))
             + (fexp2(acc[2][fn][2] - cm[fn]) + fexp2(acc[2][fn][3] - cm[fn]));
    float s3 = (fexp2(acc[3][fn][0] - cm[fn]) + fexp2(acc[3][fn][1] - cm[fn]))
             + (fexp2(acc[3][fn][2] - cm[fn]) + fexp2(acc[3][fn][3] - cm[fn]));
    cs[fn] = (s0 + s1) + (s2 + s3);
  }
  {
    float t0 = __shfl_xor(cs[0], 16), t1 = __shfl_xor(cs[1], 16),
          t2 = __shfl_xor(cs[2], 16), t3 = __shfl_xor(cs[3], 16);
    cs[0] += t0; cs[1] += t1; cs[2] += t2; cs[3] += t3;
    t0 = __shfl_xor(cs[0], 32); t1 = __shfl_xor(cs[1], 32);
    t2 = __shfl_xor(cs[2], 32); t3 = __shfl_xor(cs[3], 32);
    cs[0] += t0; cs[1] += t1; cs[2] += t2; cs[3] += t3;
  }

  const int cblk = tm * 2 + wm;
  if (lg == 0) {
#pragma unroll
    for (int fn = 0; fn < 4; ++fn)
      colp[(size_t)cblk * NN + (cbase + fn * 16 + lr)] = make_float2(cm[fn], cs[fn]);
  }
}

// WG handles 32 samples: stage [128 blocks][32 samples] slab through padded LDS
// (coalesced global reads), 8 threads per sample merge 128 partials in 2 passes.
__global__ __launch_bounds__(256) void
lsl_merge_kernel(const float2* __restrict__ rowp, const float2* __restrict__ colp,
                 const float* __restrict__ diag, float* __restrict__ bsum) {
  __shared__ float2 sl[128 * 33];
  __shared__ float2 red[32][8];
  const int tid = threadIdx.x;
  const int ibase = blockIdx.x * 32;
  const int s = tid & 31, p = tid >> 5;

  float lse0 = 0.f, lse1 = 0.f;
#pragma unroll
  for (int pass = 0; pass < 2; ++pass) {
    const float2* __restrict__ src = pass ? colp : rowp;
#pragma unroll
    for (int k = 0; k < 16; ++k) {
      int L = tid + k * 256;
      int b = L >> 5, di = L & 31;
      sl[b * 33 + di] = src[(size_t)b * NN + ibase + di];
    }
    __syncthreads();
    float m = SENT;
#pragma unroll
    for (int k = 0; k < 16; ++k) m = fmaxf(m, sl[(p * 16 + k) * 33 + s].x);
    float sum = 0.f;
#pragma unroll
    for (int k = 0; k < 16; ++k) {
      float2 v = sl[(p * 16 + k) * 33 + s];
      sum += v.y * fexp2(v.x - m);
    }
    red[s][p] = make_float2(m, sum);
    __syncthreads();
    if (p == 0) {
      float M = SENT;
#pragma unroll
      for (int k = 0; k < 8; ++k) M = fmaxf(M, red[s][k].x);
      float S = 0.f;
#pragma unroll
      for (int k = 0; k < 8; ++k) S += red[s][k].y * fexp2(red[s][k].x - M);
      if (pass == 0) lse0 = M + flog2(S); else lse1 = M + flog2(S);
    }
    __syncthreads();
  }

  if (tid < 32) {
    float loss = lse0 + lse1 - 2.f * diag[ibase + tid];   // log2 units
#pragma unroll
    for (int d = 1; d < 32; d <<= 1) loss += __shfl_xor(loss, d);
    if (tid == 0) bsum[blockIdx.x] = loss;
  }
}

__global__ __launch_bounds__(256) void
lsl_final_kernel(const float* __restrict__ bsum, float* __restrict__ out) {
  float v = bsum[threadIdx.x];
#pragma unroll
  for (int d = 1; d < 64; d <<= 1) v += __shfl_xor(v, d);
  __shared__ float l4[4];
  if ((threadIdx.x & 63) == 0) l4[threadIdx.x >> 6] = v;
  __syncthreads();
  if (threadIdx.x == 0) out[0] = (l4[0] + l4[1] + l4[2] + l4[3]) * (LN2 / (float)NN);
}

extern "C" void kernel_launch(void* const* d_in, const int* in_sizes, int n_in,
                              void* d_out, int out_size, void* d_ws, size_t ws_size,
                              hipStream_t stream) {
  const float* A = (const float*)d_in[0];
  const float* T = (const float*)d_in[1];
  const int* fids = (const int*)d_in[2];
  float* out = (float*)d_out;
  char* ws = (char*)d_ws;

  // ws: Ab 2MB | Tb 2MB | diag 32KB | rowp 8MB | colp 8MB | bsum 1KB
  size_t off = 0;
  ushort* Ab  = (ushort*)(ws + off); off += (size_t)NN * EE * 2;
  ushort* Tb  = (ushort*)(ws + off); off += (size_t)NN * EE * 2;
  float* diag = (float*)(ws + off);  off += (size_t)NN * 4;
  float2* rowp = (float2*)(ws + off); off += (size_t)NN * 128 * 8;
  float2* colp = (float2*)(ws + off); off += (size_t)NN * 128 * 8;
  float* bsum = (float*)(ws + off);  off += 1024;

  hipLaunchKernelGGL(lsl_cvt_kernel, dim3(NN * EE / 4 / 256), dim3(256), 0, stream, A, T, Ab, Tb, diag);
  hipLaunchKernelGGL(lsl_tile_kernel, dim3(4096), dim3(256), 0, stream, Ab, Tb, fids, rowp, colp);
  hipLaunchKernelGGL(lsl_merge_kernel, dim3(NN / 32), dim3(256), 0, stream, rowp, colp, diag, bsum);
  hipLaunchKernelGGL(lsl_final_kernel, dim3(1), dim3(256), 0, stream, bsum, out);
}

// Round 10
// 62.359 us; speedup vs baseline: 1.8654x; 1.0315x over previous
//
#include <hip/hip_runtime.h>
#include <hip/hip_bf16.h>
#include <math.h>

#define NN 8192
#define EE 128

static constexpr float INV_T = 1.0f / 0.07f;
static constexpr float LOG2E = 1.4426950408889634f;
static constexpr float LN2   = 0.6931471805599453f;
static constexpr float SENT  = -3.0e38f;

typedef __attribute__((ext_vector_type(8))) short fragAB;   // 8 bf16
typedef __attribute__((ext_vector_type(4))) float f32x4;
typedef const __attribute__((address_space(1))) void gvoid;
typedef __attribute__((address_space(3))) void lvoid;

__device__ inline float fexp2(float x) { float r; asm("v_exp_f32 %0, %1" : "=v"(r) : "v"(x)); return r; }
__device__ inline float flog2(float x) { float r; asm("v_log_f32 %0, %1" : "=v"(r) : "v"(x)); return r; }

template<int CTRL>
__device__ inline float dpp_f(float x) {
  return __builtin_bit_cast(float,
      __builtin_amdgcn_update_dpp(0, __builtin_bit_cast(int, x), CTRL, 0xf, 0xf, true));
}
__device__ inline float red16_max(float x) {
  x = fmaxf(x, dpp_f<0xB1>(x));    // quad_perm [1,0,3,2]
  x = fmaxf(x, dpp_f<0x4E>(x));    // quad_perm [2,3,0,1]
  x = fmaxf(x, dpp_f<0x141>(x));   // row_half_mirror
  x = fmaxf(x, dpp_f<0x140>(x));   // row_mirror
  return x;
}
__device__ inline float red16_add(float x) {
  x += dpp_f<0xB1>(x); x += dpp_f<0x4E>(x); x += dpp_f<0x141>(x); x += dpp_f<0x140>(x);
  return x;
}

__device__ inline ushort f32_to_bf16_bits(float x) {
  union { float f; unsigned u; } c; c.f = x;
  unsigned u = c.u;
  u += 0x7fffu + ((u >> 16) & 1u);   // RNE
  return (ushort)(u >> 16);
}

// fp32 -> bf16 (A pre-scaled by 1/temp*log2e so scores are log2-domain),
// plus exact fp32 diagonal dot products (log2 units).
__global__ void lsl_cvt_kernel(const float* __restrict__ A, const float* __restrict__ T,
                               ushort* __restrict__ Ab, ushort* __restrict__ Tb,
                               float* __restrict__ diag) {
  const int t = blockIdx.x * 256 + threadIdx.x;
  const int i = t * 4;
  float4 a = *reinterpret_cast<const float4*>(A + i);
  float4 tt = *reinterpret_cast<const float4*>(T + i);
  ushort4 oa, ot;
  const float SC = INV_T * LOG2E;
  oa.x = f32_to_bf16_bits(a.x * SC); oa.y = f32_to_bf16_bits(a.y * SC);
  oa.z = f32_to_bf16_bits(a.z * SC); oa.w = f32_to_bf16_bits(a.w * SC);
  ot.x = f32_to_bf16_bits(tt.x); ot.y = f32_to_bf16_bits(tt.y);
  ot.z = f32_to_bf16_bits(tt.z); ot.w = f32_to_bf16_bits(tt.w);
  *reinterpret_cast<ushort4*>(Ab + i) = oa;
  *reinterpret_cast<ushort4*>(Tb + i) = ot;

  float pd = a.x * tt.x + a.y * tt.y + a.z * tt.z + a.w * tt.w;
  pd += __shfl_xor(pd, 1); pd += __shfl_xor(pd, 2); pd += __shfl_xor(pd, 4);
  pd += __shfl_xor(pd, 8); pd += __shfl_xor(pd, 16);
  if ((threadIdx.x & 31) == 0) diag[i >> 7] = pd * (INV_T * LOG2E);   // log2 units
}

#define MMAC(av, bv)                                                              \
  _Pragma("unroll") for (int fm = 0; fm < 4; ++fm)                                \
    _Pragma("unroll") for (int fn = 0; fn < 4; ++fn)                              \
      acc[fm][fn] = __builtin_amdgcn_mfma_f32_16x16x32_bf16(av[fm], bv[fn], acc[fm][fn], 0, 0, 0);

// WG = 128x128 tile (4 waves 2x2, 64x64 per wave). Full A/B tiles staged to
// LDS via global_load_lds width-16 (one async burst, one barrier), LDS
// XOR-swizzled (linear dest + pre-swizzled global source, same XOR on read).
// Epilogue: single read-once sweep of acc into masked VGPR temporaries (avoids
// AGPR<->VGPR ping-pong), then stage-major reduction trees.
__global__ __launch_bounds__(256) void
lsl_tile_kernel(const ushort* __restrict__ Ab, const ushort* __restrict__ Tb,
                const int* __restrict__ fids,
                float2* __restrict__ rowp, float2* __restrict__ colp) {
  __shared__ ushort As[128 * 128];
  __shared__ ushort Bs[128 * 128];

  const int bid = blockIdx.x;
  const int swz = (bid & 7) * 512 + (bid >> 3);   // bijective XCD chunking (4096 WGs)
  const int tm = swz >> 6, tn = swz & 63;
  const int tid = threadIdx.x;
  const int lane = tid & 63;
  const int wid  = tid >> 6;
  const int wm = wid >> 1, wn = wid & 1;
  const int rbase = tm * 128 + wm * 64;
  const int cbase = tn * 128 + wn * 64;
  const int lr = lane & 15, lg = lane >> 4;

  // ---- stage both tiles: linear LDS dest, pre-swizzled global source ----
  {
    const int trow = tid >> 4;
    const int scol = ((tid & 15) ^ trow) * 8;
    const ushort* gA = Ab + (size_t)(tm * 128 + trow) * EE + scol;
    const ushort* gB = Tb + (size_t)(tn * 128 + trow) * EE + scol;
#pragma unroll
    for (int i = 0; i < 8; ++i)
      __builtin_amdgcn_global_load_lds((gvoid*)(gA + (size_t)i * 16 * EE),
          (lvoid*)((char*)As + i * 4096 + wid * 1024), 16, 0, 0);
#pragma unroll
    for (int i = 0; i < 8; ++i)
      __builtin_amdgcn_global_load_lds((gvoid*)(gB + (size_t)i * 16 * EE),
          (lvoid*)((char*)Bs + i * 4096 + wid * 1024), 16, 0, 0);
  }
  __syncthreads();

  // ---- compute from LDS ----
  f32x4 acc[4][4] = {};   // D: col = lane&15, row = (lane>>4)*4 + reg
#pragma unroll
  for (int ks = 0; ks < 4; ++ks) {
    fragAB av[4], bv[4];
#pragma unroll
    for (int f = 0; f < 4; ++f) {
      av[f] = *reinterpret_cast<const fragAB*>(
          &As[(wm * 64 + f * 16 + lr) * 128 + (((ks * 4 + lg) ^ lr) * 8)]);
      bv[f] = *reinterpret_cast<const fragAB*>(
          &Bs[(wn * 64 + f * 16 + lr) * 128 + (((ks * 4 + lg) ^ lr) * 8)]);
    }
    MMAC(av, bv)
  }

  // fids
  int fr[4][4], fc[4];
#pragma unroll
  for (int fm = 0; fm < 4; ++fm) {
    int4 v4 = *reinterpret_cast<const int4*>(fids + rbase + fm * 16 + lg * 4);
    fr[fm][0] = v4.x; fr[fm][1] = v4.y; fr[fm][2] = v4.z; fr[fm][3] = v4.w;
  }
#pragma unroll
  for (int fn = 0; fn < 4; ++fn) fc[fn] = fids[cbase + fn * 16 + lr];

  // ---- single read-once sweep: acc -> masked VGPR copies ----
  float e[4][4][4];   // [fm][fn][r]
  const bool diagtile = (rbase == cbase);
#pragma unroll
  for (int fm = 0; fm < 4; ++fm)
#pragma unroll
    for (int fn = 0; fn < 4; ++fn)
#pragma unroll
      for (int r = 0; r < 4; ++r) {
        float v = acc[fm][fn][r];
        bool keep = (fr[fm][r] != fc[fn]) || (diagtile && fm == fn && lr == lg * 4 + r);
        e[fm][fn][r] = keep ? v : SENT;
      }

  // ---------- row pass, stage-major ----------
  float rm[4][4];
#pragma unroll
  for (int fm = 0; fm < 4; ++fm)
#pragma unroll
    for (int r = 0; r < 4; ++r)
      rm[fm][r] = fmaxf(fmaxf(e[fm][0][r], e[fm][1][r]),
                        fmaxf(e[fm][2][r], e[fm][3][r]));
#pragma unroll
  for (int fm = 0; fm < 4; ++fm)
#pragma unroll
    for (int r = 0; r < 4; ++r)
      rm[fm][r] = red16_max(rm[fm][r]);

  float rs[4][4];
#pragma unroll
  for (int fm = 0; fm < 4; ++fm)
#pragma unroll
    for (int r = 0; r < 4; ++r)
      rs[fm][r] = (fexp2(e[fm][0][r] - rm[fm][r]) + fexp2(e[fm][1][r] - rm[fm][r]))
                + (fexp2(e[fm][2][r] - rm[fm][r]) + fexp2(e[fm][3][r] - rm[fm][r]));
#pragma unroll
  for (int fm = 0; fm < 4; ++fm)
#pragma unroll
    for (int r = 0; r < 4; ++r)
      rs[fm][r] = red16_add(rs[fm][r]);

  const int rblk = tn * 2 + wn;
  if (lr == 0) {
#pragma unroll
    for (int fm = 0; fm < 4; ++fm)
#pragma unroll
      for (int r = 0; r < 4; ++r)
        rowp[(size_t)rblk * NN + (rbase + fm * 16 + lg * 4 + r)] = make_float2(rm[fm][r], rs[fm][r]);
  }

  // ---------- col pass, stage-major ----------
  float cm[4];
#pragma unroll
  for (int fn = 0; fn < 4; ++fn) {
    float m0 = fmaxf(fmaxf(e[0][fn][0], e[0][fn][1]), fmaxf(e[0][fn][2], e[0][fn][3]));
    float m1 = fmaxf(fmaxf(e[1][fn][0], e[1][fn][1]), fmaxf(e[1][fn][2], e[1][fn][3]));
    float m2 = fmaxf(fmaxf(e[2][fn][0], e[2][fn][1]), fmaxf(e[2][fn][2], e[2][fn][3]));
    float m3 = fmaxf(fmaxf(e[3][fn][0], e[3][fn][1]), fmaxf(e[3][fn][2], e[3][fn][3]));
    cm[fn] = fmaxf(fmaxf(m0, m1), fmaxf(m2, m3));
  }
  {
    float t0 = __shfl_xor(cm[0], 16), t1 = __shfl_xor(cm[1], 16),
          t2 = __shfl_xor(cm[2], 16), t3 = __shfl_xor(cm[3], 16);
    cm[0] = fmaxf(cm[0], t0); cm[1] = fmaxf(cm[1], t1);
    cm[2] = fmaxf(cm[2], t2); cm[3] = fmaxf(cm[3], t3);
    t0 = __shfl_xor(cm[0], 32); t1 = __shfl_xor(cm[1], 32);
    t2 = __shfl_xor(cm[2], 32); t3 = __shfl_xor(cm[3], 32);
    cm[0] = fmaxf(cm[0], t0); cm[1] = fmaxf(cm[1], t1);
    cm[2] = fmaxf(cm[2], t2); cm[3] = fmaxf(cm[3], t3);
  }
  float cs[4];
#pragma unroll
  for (int fn = 0; fn < 4; ++fn) {
    float s0 = (fexp2(e[0][fn][0] - cm[fn]) + fexp2(e[0][fn][1] - cm[fn]))
             + (fexp2(e[0][fn][2] - cm[fn]) + fexp2(e[0][fn][3] - cm[fn]));
    float s1 = (fexp2(e[1][fn][0] - cm[fn]) + fexp2(e[1][fn][1] - cm[fn]))
             + (fexp2(e[1][fn][2] - cm[fn]) + fexp2(e[1][fn][3] - cm[fn]));
    float s2 = (fexp2(e[2][fn][0] - cm[fn]) + fexp2(e[2][fn][1] - cm[fn]))
             + (fexp2(e[2][fn][2] - cm[fn]) + fexp2(e[2][fn][3] - cm[fn]));
    float s3 = (fexp2(e[3][fn][0] - cm[fn]) + fexp2(e[3][fn][1] - cm[fn]))
             + (fexp2(e[3][fn][2] - cm[fn]) + fexp2(e[3][fn][3] - cm[fn]));
    cs[fn] = (s0 + s1) + (s2 + s3);
  }
  {
    float t0 = __shfl_xor(cs[0], 16), t1 = __shfl_xor(cs[1], 16),
          t2 = __shfl_xor(cs[2], 16), t3 = __shfl_xor(cs[3], 16);
    cs[0] += t0; cs[1] += t1; cs[2] += t2; cs[3] += t3;
    t0 = __shfl_xor(cs[0], 32); t1 = __shfl_xor(cs[1], 32);
    t2 = __shfl_xor(cs[2], 32); t3 = __shfl_xor(cs[3], 32);
    cs[0] += t0; cs[1] += t1; cs[2] += t2; cs[3] += t3;
  }

  const int cblk = tm * 2 + wm;
  if (lg == 0) {
#pragma unroll
    for (int fn = 0; fn < 4; ++fn)
      colp[(size_t)cblk * NN + (cbase + fn * 16 + lr)] = make_float2(cm[fn], cs[fn]);
  }
}

// WG handles 32 samples: stage [128 blocks][32 samples] slab through padded LDS
// (coalesced global reads), 8 threads per sample merge 128 partials in 2 passes.
__global__ __launch_bounds__(256) void
lsl_merge_kernel(const float2* __restrict__ rowp, const float2* __restrict__ colp,
                 const float* __restrict__ diag, float* __restrict__ bsum) {
  __shared__ float2 sl[128 * 33];
  __shared__ float2 red[32][8];
  const int tid = threadIdx.x;
  const int ibase = blockIdx.x * 32;
  const int s = tid & 31, p = tid >> 5;

  float lse0 = 0.f, lse1 = 0.f;
#pragma unroll
  for (int pass = 0; pass < 2; ++pass) {
    const float2* __restrict__ src = pass ? colp : rowp;
#pragma unroll
    for (int k = 0; k < 16; ++k) {
      int L = tid + k * 256;
      int b = L >> 5, di = L & 31;
      sl[b * 33 + di] = src[(size_t)b * NN + ibase + di];
    }
    __syncthreads();
    float m = SENT;
#pragma unroll
    for (int k = 0; k < 16; ++k) m = fmaxf(m, sl[(p * 16 + k) * 33 + s].x);
    float sum = 0.f;
#pragma unroll
    for (int k = 0; k < 16; ++k) {
      float2 v = sl[(p * 16 + k) * 33 + s];
      sum += v.y * fexp2(v.x - m);
    }
    red[s][p] = make_float2(m, sum);
    __syncthreads();
    if (p == 0) {
      float M = SENT;
#pragma unroll
      for (int k = 0; k < 8; ++k) M = fmaxf(M, red[s][k].x);
      float S = 0.f;
#pragma unroll
      for (int k = 0; k < 8; ++k) S += red[s][k].y * fexp2(red[s][k].x - M);
      if (pass == 0) lse0 = M + flog2(S); else lse1 = M + flog2(S);
    }
    __syncthreads();
  }

  if (tid < 32) {
    float loss = lse0 + lse1 - 2.f * diag[ibase + tid];   // log2 units
#pragma unroll
    for (int d = 1; d < 32; d <<= 1) loss += __shfl_xor(loss, d);
    if (tid == 0) bsum[blockIdx.x] = loss;
  }
}

__global__ __launch_bounds__(256) void
lsl_final_kernel(const float* __restrict__ bsum, float* __restrict__ out) {
  float v = bsum[threadIdx.x];
#pragma unroll
  for (int d = 1; d < 64; d <<= 1) v += __shfl_xor(v, d);
  __shared__ float l4[4];
  if ((threadIdx.x & 63) == 0) l4[threadIdx.x >> 6] = v;
  __syncthreads();
  if (threadIdx.x == 0) out[0] = (l4[0] + l4[1] + l4[2] + l4[3]) * (LN2 / (float)NN);
}

extern "C" void kernel_launch(void* const* d_in, const int* in_sizes, int n_in,
                              void* d_out, int out_size, void* d_ws, size_t ws_size,
                              hipStream_t stream) {
  const float* A = (const float*)d_in[0];
  const float* T = (const float*)d_in[1];
  const int* fids = (const int*)d_in[2];
  float* out = (float*)d_out;
  char* ws = (char*)d_ws;

  // ws: Ab 2MB | Tb 2MB | diag 32KB | rowp 8MB | colp 8MB | bsum 1KB
  size_t off = 0;
  ushort* Ab  = (ushort*)(ws + off); off += (size_t)NN * EE * 2;
  ushort* Tb  = (ushort*)(ws + off); off += (size_t)NN * EE * 2;
  float* diag = (float*)(ws + off);  off += (size_t)NN * 4;
  float2* rowp = (float2*)(ws + off); off += (size_t)NN * 128 * 8;
  float2* colp = (float2*)(ws + off); off += (size_t)NN * 128 * 8;
  float* bsum = (float*)(ws + off);  off += 1024;

  hipLaunchKernelGGL(lsl_cvt_kernel, dim3(NN * EE / 4 / 256), dim3(256), 0, stream, A, T, Ab, Tb, diag);
  hipLaunchKernelGGL(lsl_tile_kernel, dim3(4096), dim3(256), 0, stream, Ab, Tb, fids, rowp, colp);
  hipLaunchKernelGGL(lsl_merge_kernel, dim3(NN / 32), dim3(256), 0, stream, rowp, colp, diag, bsum);
  hipLaunchKernelGGL(lsl_final_kernel, dim3(1), dim3(256), 0, stream, bsum, out);
}